// Round 11
// baseline (38.070 us; speedup 1.0000x reference)
//
#include <hip/hip_runtime.h>

// ConvCapsules2d:
//  activations: [8,32,14,14] f32
//  poses:       [8,32,4,4,14,14] f32   (n,b,i,m,h,w)
//  W_ij:        [32,32,4,4,3,3] f32    (b,c,m,j,k,l)
// Outputs (concatenated flat):
//  acts_out: [8,32,6,6,3,3]                  = 82944 f32
//  V_ji:     [8,32,32,16,6,6,3,3]            = 42467328 f32
// V[n,b,c,i,j,f,g,k,l] = sum_m poses[n,b,i,m,f*2+k,g*2+l] * W[b,c,m,j,k,l]
// r = f*54 + g*9 + k*3 + l ; wo(r) = r%9 ; po(r) = (f*2+k)*14 + (g*2+l)
//
// v10 = v8 inner loop/stores, but each block covers an r-HALF (162 r's).
// r<162 -> h=f*2+k in [0,6]; r>=162 -> h in [6,12]: 7 pose rows each.
// Pl2 shrinks 15.7->7.8 KB, LDS total ~14.3 KB, grid 2048,
// __launch_bounds__(256,6) -> ~6 blocks/CU resident + queue => staggered
// phases: one block's staging overlaps others' stores.

#define RLEN 324
#define RHALF 162
#define ACTS_OUT 82944
#define PSTRIDE 20          // dwords per padded row (16 data + 4 pad)
#define CPB 8               // c's per block
#define ITEMS (CPB * RHALF) // 1296 work items per block
#define POROWS 98           // 7 h-rows * 14 w

__device__ __forceinline__ int po_of(int r) {
    int f = r / 54;  int r1 = r - f * 54;
    int g = r1 / 9;  int r2 = r1 - g * 9;
    int k = r2 / 3;  int l  = r2 - k * 3;
    return (f * 2 + k) * 14 + (g * 2 + l);
}

// grid = 2048: bid = nb*8 + cq*2 + half
__global__ __launch_bounds__(256, 6) void v10_kernel(const float* __restrict__ act,
                                                     const float* __restrict__ poses,
                                                     const float* __restrict__ W,
                                                     float* __restrict__ out) {
    __shared__ float    Pl2[POROWS * PSTRIDE];  // [po_local][i*4+m], 7.84 KB
    __shared__ float    Wall[CPB][9 * PSTRIDE]; // [cl][wo][m*4+j], 5.76 KB
    __shared__ unsigned tbl[RHALF];             // po_local | wo<<16

    const int bid  = blockIdx.x;
    const int nb   = bid >> 3;                  // n*32 + b
    const int cq   = (bid >> 1) & 3;
    const int half = bid & 1;
    const int b    = nb & 31;
    const int tid  = threadIdx.x;
    const int rbase = half * RHALF;
    const int pobase = half * 84;               // h0*14, h0 = 6*half

    // ---- stage pose rows h in [6*half, 6*half+6]: 392 float4
    const float* pn = poses + (size_t)nb * 3136 + pobase;
    for (int t = tid; t < 4 * POROWS; t += 256) {
        int i  = t / POROWS;
        int pl = t - i * POROWS;
        float4 v;
        v.x = pn[(i * 4 + 0) * 196 + pl];
        v.y = pn[(i * 4 + 1) * 196 + pl];
        v.z = pn[(i * 4 + 2) * 196 + pl];
        v.w = pn[(i * 4 + 3) * 196 + pl];
        *(float4*)&Pl2[pl * PSTRIDE + i * 4] = v;
    }
    // ---- stage W[b, cq*8 .. cq*8+7] transposed: Wall[cl][wo][m*4+j]
    for (int t = tid; t < CPB * 36; t += 256) {
        int cl = t / 36;
        int s  = t - cl * 36;
        int wo = s >> 2, m = s & 3;
        const float* wb = W + ((size_t)(b * 32 + cq * CPB + cl)) * 144 + m * 36 + wo;
        float4 v;
        v.x = wb[0 * 9];
        v.y = wb[1 * 9];
        v.z = wb[2 * 9];
        v.w = wb[3 * 9];
        *(float4*)&Wall[cl][wo * PSTRIDE + m * 4] = v;
    }
    // ---- packed (po_local, wo) table for this r-half
    for (int rl = tid; rl < RHALF; rl += 256) {
        int r = rbase + rl;
        tbl[rl] = (unsigned)(po_of(r) - pobase) | ((unsigned)(r % 9) << 16);
    }
    __syncthreads();

    // ---- fused acts_out gather (cq==0 blocks; each half does its r-range)
    if (cq == 0) {
        const float* an = act + (size_t)nb * 196 + pobase;
        for (int a = tid; a < RHALF; a += 256)
            out[nb * RLEN + rbase + a] = an[tbl[a] & 0xffffu];
    }

    // ---- main compute/store loop: 16 outputs per item (v8-identical)
    for (int item = tid; item < ITEMS; item += 256) {
        unsigned cl = (unsigned)item / RHALF;
        int rl = item - (int)cl * RHALF;
        unsigned pk = tbl[rl];
        int po = (int)(pk & 0xffffu);
        int wo = (int)(pk >> 16);

        const float* Pb = &Pl2[po * PSTRIDE];
        const float* Wb = &Wall[cl][wo * PSTRIDE];
        float4 p0 = *(const float4*)&Pb[0];     // i=0: m0..3
        float4 p1 = *(const float4*)&Pb[4];
        float4 p2 = *(const float4*)&Pb[8];
        float4 p3 = *(const float4*)&Pb[12];
        float4 w0 = *(const float4*)&Wb[0];     // m=0: j0..3
        float4 w1 = *(const float4*)&Wb[4];
        float4 w2 = *(const float4*)&Wb[8];
        float4 w3 = *(const float4*)&Wb[12];

        int c = cq * CPB + (int)cl;
        float* obase = out + ACTS_OUT + ((size_t)(nb * 32 + c)) * 5184 + rbase + rl;
        #pragma unroll
        for (int i = 0; i < 4; ++i) {
            float4 pi = (i == 0) ? p0 : (i == 1) ? p1 : (i == 2) ? p2 : p3;
            float4 v;
            v.x = pi.x * w0.x + pi.y * w1.x + pi.z * w2.x + pi.w * w3.x;
            v.y = pi.x * w0.y + pi.y * w1.y + pi.z * w2.y + pi.w * w3.y;
            v.z = pi.x * w0.z + pi.y * w1.z + pi.z * w2.z + pi.w * w3.z;
            v.w = pi.x * w0.w + pi.y * w1.w + pi.z * w2.w + pi.w * w3.w;
            obase[(i * 4 + 0) * RLEN] = v.x;    // lanes: consecutive r -> coalesced
            obase[(i * 4 + 1) * RLEN] = v.y;
            obase[(i * 4 + 2) * RLEN] = v.z;
            obase[(i * 4 + 3) * RLEN] = v.w;
        }
    }
}

extern "C" void kernel_launch(void* const* d_in, const int* in_sizes, int n_in,
                              void* d_out, int out_size, void* d_ws, size_t ws_size,
                              hipStream_t stream) {
    const float* act   = (const float*)d_in[0];
    const float* poses = (const float*)d_in[1];
    const float* W     = (const float*)d_in[2];
    float* out = (float*)d_out;

    v10_kernel<<<2048, 256, 0, stream>>>(act, poses, W, out);
}

// Round 12
// 36.689 us; speedup vs baseline: 1.0376x; 1.0376x over previous
//
#include <hip/hip_runtime.h>

// ConvCapsules2d:
//  activations: [8,32,14,14] f32
//  poses:       [8,32,4,4,14,14] f32   (n,b,i,m,h,w)
//  W_ij:        [32,32,4,4,3,3] f32    (b,c,m,j,k,l)
// Outputs (concatenated flat):
//  acts_out: [8,32,6,6,3,3]                  = 82944 f32
//  V_ji:     [8,32,32,16,6,6,3,3]            = 42467328 f32
// V[n,b,c,i,j,f,g,k,l] = sum_m poses[n,b,i,m,f*2+k,g*2+l] * W[b,c,m,j,k,l]
// r = f*54 + g*9 + k*3 + l ; wo(r) = r%9 ; po(r) = (f*2+k)*14 + (g*2+l)
//
// v11 = v8 staging/fragments + LDS-staged output tile per c:
// compute phase writes obuf[ij*324+r] (output layout), store phase flat-copies
// the 20.7 KB tile as contiguous dwordx4 wave bursts (fill-kernel pattern).
// Isolates "DRAM-level store stream locality" with LDS kept cheap.

#define RLEN 324
#define ACTS_OUT 82944
#define PSTRIDE 20          // dwords per padded row (16 data + 4 pad)
#define CPB 8               // c's per block

__device__ __forceinline__ int po_of(int r) {
    int f = r / 54;  int r1 = r - f * 54;
    int g = r1 / 9;  int r2 = r1 - g * 9;
    int k = r2 / 3;  int l  = r2 - k * 3;
    return (f * 2 + k) * 14 + (g * 2 + l);
}

// grid = 1024: bid = nb*4 + cq ; block covers c = cq*8 .. cq*8+7
__global__ __launch_bounds__(256, 3) void v11_kernel(const float* __restrict__ act,
                                                     const float* __restrict__ poses,
                                                     const float* __restrict__ W,
                                                     float* __restrict__ out) {
    __shared__ float    Pl2[196 * PSTRIDE];     // [po][i*4+m], 15.68 KB
    __shared__ float    Wall[CPB][9 * PSTRIDE]; // [cl][wo][m*4+j], 5.76 KB
    __shared__ unsigned tbl[RLEN];              // po | wo<<16, 1.30 KB
    __shared__ float    obuf[16 * RLEN];        // output tile for one c, 20.74 KB

    const int bid = blockIdx.x;
    const int nb  = bid >> 2;                   // n*32 + b
    const int cq  = bid & 3;
    const int b   = nb & 31;
    const int tid = threadIdx.x;

    // ---- stage poses[n,b] transposed (once per block)
    const float* pn = poses + (size_t)nb * 3136;
    for (int t = tid; t < 784; t += 256) {
        int i  = t / 196;
        int po = t - i * 196;
        float4 v;
        v.x = pn[(i * 4 + 0) * 196 + po];
        v.y = pn[(i * 4 + 1) * 196 + po];
        v.z = pn[(i * 4 + 2) * 196 + po];
        v.w = pn[(i * 4 + 3) * 196 + po];
        *(float4*)&Pl2[po * PSTRIDE + i * 4] = v;
    }
    // ---- stage W[b, cq*8 .. cq*8+7] transposed: Wall[cl][wo][m*4+j]
    for (int t = tid; t < CPB * 36; t += 256) {
        int cl = t / 36;
        int s  = t - cl * 36;
        int wo = s >> 2, m = s & 3;
        const float* wb = W + ((size_t)(b * 32 + cq * CPB + cl)) * 144 + m * 36 + wo;
        float4 v;
        v.x = wb[0 * 9];
        v.y = wb[1 * 9];
        v.z = wb[2 * 9];
        v.w = wb[3 * 9];
        *(float4*)&Wall[cl][wo * PSTRIDE + m * 4] = v;
    }
    // ---- packed (po, wo) table
    for (int r = tid; r < RLEN; r += 256)
        tbl[r] = (unsigned)po_of(r) | ((unsigned)(r % 9) << 16);
    __syncthreads();

    // ---- fused acts_out gather (only cq==0 blocks)
    if (cq == 0) {
        const float* an = act + (size_t)nb * 196;
        for (int a = tid; a < RLEN; a += 256)
            out[nb * RLEN + a] = an[tbl[a] & 0xffffu];
    }

    // ---- per-c phases: compute tile into LDS, then flat-store it
    for (int cl = 0; cl < CPB; ++cl) {
        // compute phase: one item per r, all 16 ij
        for (int r = tid; r < RLEN; r += 256) {
            unsigned pk = tbl[r];
            int po = (int)(pk & 0xffffu);
            int wo = (int)(pk >> 16);

            const float* Pb = &Pl2[po * PSTRIDE];
            const float* Wb = &Wall[cl][wo * PSTRIDE];
            float4 p0 = *(const float4*)&Pb[0];     // i=0: m0..3
            float4 p1 = *(const float4*)&Pb[4];
            float4 p2 = *(const float4*)&Pb[8];
            float4 p3 = *(const float4*)&Pb[12];
            float4 w0 = *(const float4*)&Wb[0];     // m=0: j0..3
            float4 w1 = *(const float4*)&Wb[4];
            float4 w2 = *(const float4*)&Wb[8];
            float4 w3 = *(const float4*)&Wb[12];

            #pragma unroll
            for (int i = 0; i < 4; ++i) {
                float4 pi = (i == 0) ? p0 : (i == 1) ? p1 : (i == 2) ? p2 : p3;
                // lanes have consecutive r -> each ds_write_b32 is bank-clean
                obuf[(i * 4 + 0) * RLEN + r] = pi.x * w0.x + pi.y * w1.x + pi.z * w2.x + pi.w * w3.x;
                obuf[(i * 4 + 1) * RLEN + r] = pi.x * w0.y + pi.y * w1.y + pi.z * w2.y + pi.w * w3.y;
                obuf[(i * 4 + 2) * RLEN + r] = pi.x * w0.z + pi.y * w1.z + pi.z * w2.z + pi.w * w3.z;
                obuf[(i * 4 + 3) * RLEN + r] = pi.x * w0.w + pi.y * w1.w + pi.z * w2.w + pi.w * w3.w;
            }
        }
        __syncthreads();

        // store phase: flat contiguous copy, fill-kernel pattern
        // dst is 256B-aligned: (nb*32+c)*5184*4B = c-index * 20736B (81*256)
        float* dst = out + ACTS_OUT + ((size_t)(nb * 32 + cq * CPB + cl)) * 5184;
        for (int t = tid; t < 1296; t += 256)
            *(float4*)&dst[t * 4] = *(const float4*)&obuf[t * 4];
        __syncthreads();
    }
}

extern "C" void kernel_launch(void* const* d_in, const int* in_sizes, int n_in,
                              void* d_out, int out_size, void* d_ws, size_t ws_size,
                              hipStream_t stream) {
    const float* act   = (const float*)d_in[0];
    const float* poses = (const float*)d_in[1];
    const float* W     = (const float*)d_in[2];
    float* out = (float*)d_out;

    v11_kernel<<<1024, 256, 0, stream>>>(act, poses, W, out);
}

// Round 13
// 34.325 us; speedup vs baseline: 1.1091x; 1.0689x over previous
//
#include <hip/hip_runtime.h>

// ConvCapsules2d:
//  activations: [8,32,14,14] f32
//  poses:       [8,32,4,4,14,14] f32   (n,b,i,m,h,w)
//  W_ij:        [32,32,4,4,3,3] f32    (b,c,m,j,k,l)
// Outputs (concatenated flat):
//  acts_out: [8,32,6,6,3,3]                  = 82944 f32
//  V_ji:     [8,32,32,16,6,6,3,3]            = 42467328 f32
// V[n,b,c,i,j,f,g,k,l] = sum_m poses[n,b,i,m,f*2+k,g*2+l] * W[b,c,m,j,k,l]
// r = f*54 + g*9 + k*3 + l ; wo(r) = r%9 ; po(r) = (f*2+k)*14 + (g*2+l)
//
// FINAL = v8 (empirical minimum across 11 variants, 34.1 µs):
// CPB=8, grid 1024, one barrier, transposed padded LDS fragments
// (0.5 ds_read_b128 per output), scalar coalesced stores.
// Measured ladder: v4 35.5 / v5(nt) 76.6 / v6 37.2 / v7 64.0 / v8 34.1 /
// v9 35.0 / v10 38.1 / v11 36.7. Store floor ~25-26.5 µs (fill-kernel ref).

#define RLEN 324
#define ACTS_OUT 82944
#define PSTRIDE 20          // dwords per padded row (16 data + 4 pad)
#define CPB 8               // c's per block
#define ITEMS (CPB * RLEN)  // 2592 work items per block

__device__ __forceinline__ int po_of(int r) {
    int f = r / 54;  int r1 = r - f * 54;
    int g = r1 / 9;  int r2 = r1 - g * 9;
    int k = r2 / 3;  int l  = r2 - k * 3;
    return (f * 2 + k) * 14 + (g * 2 + l);
}

// grid = 1024: bid = nb*4 + cq ; block covers c = cq*8 .. cq*8+7
__global__ __launch_bounds__(256, 4) void v8_kernel(const float* __restrict__ act,
                                                    const float* __restrict__ poses,
                                                    const float* __restrict__ W,
                                                    float* __restrict__ out) {
    __shared__ float Pl2[196 * PSTRIDE];        // Pl2[po][i*4+m], 15.7 KB
    __shared__ float Wall[CPB][9 * PSTRIDE];    // Wall[cl][wo][m*4+j], 5.8 KB

    const int bid = blockIdx.x;
    const int nb  = bid >> 2;                   // n*32 + b
    const int cq  = bid & 3;
    const int b   = nb & 31;
    const int tid = threadIdx.x;

    // ---- stage poses[n,b] transposed (once per block)
    const float* pn = poses + (size_t)nb * 3136;
    for (int t = tid; t < 784; t += 256) {
        int i  = t / 196;
        int po = t - i * 196;
        float4 v;
        v.x = pn[(i * 4 + 0) * 196 + po];
        v.y = pn[(i * 4 + 1) * 196 + po];
        v.z = pn[(i * 4 + 2) * 196 + po];
        v.w = pn[(i * 4 + 3) * 196 + po];
        *(float4*)&Pl2[po * PSTRIDE + i * 4] = v;
    }
    // ---- stage W[b, cq*8 .. cq*8+7] transposed: Wall[cl][wo][m*4+j]
    for (int t = tid; t < CPB * 36; t += 256) {
        int cl = t / 36;
        int s  = t - cl * 36;
        int wo = s >> 2, m = s & 3;
        const float* wb = W + ((size_t)(b * 32 + cq * CPB + cl)) * 144 + m * 36 + wo;
        float4 v;
        v.x = wb[0 * 9];
        v.y = wb[1 * 9];
        v.z = wb[2 * 9];
        v.w = wb[3 * 9];
        *(float4*)&Wall[cl][wo * PSTRIDE + m * 4] = v;
    }
    __syncthreads();

    // ---- fused acts_out gather (only cq==0 blocks)
    if (cq == 0) {
        const float* an = act + (size_t)nb * 196;
        for (int a = tid; a < RLEN; a += 256)
            out[nb * RLEN + a] = an[po_of(a)];
    }

    // ---- main compute/store loop: 16 outputs per item
    for (int item = tid; item < ITEMS; item += 256) {
        unsigned cl = (unsigned)item / RLEN;
        int r  = item - (int)cl * RLEN;
        int po = po_of(r);
        int wo = r % 9;

        const float* Pb = &Pl2[po * PSTRIDE];
        const float* Wb = &Wall[cl][wo * PSTRIDE];
        float4 p0 = *(const float4*)&Pb[0];     // i=0: m0..3
        float4 p1 = *(const float4*)&Pb[4];
        float4 p2 = *(const float4*)&Pb[8];
        float4 p3 = *(const float4*)&Pb[12];
        float4 w0 = *(const float4*)&Wb[0];     // m=0: j0..3
        float4 w1 = *(const float4*)&Wb[4];
        float4 w2 = *(const float4*)&Wb[8];
        float4 w3 = *(const float4*)&Wb[12];

        int c = cq * CPB + (int)cl;
        float* obase = out + ACTS_OUT + ((size_t)(nb * 32 + c)) * 5184 + r;
        #pragma unroll
        for (int i = 0; i < 4; ++i) {
            float4 pi = (i == 0) ? p0 : (i == 1) ? p1 : (i == 2) ? p2 : p3;
            float4 v;
            v.x = pi.x * w0.x + pi.y * w1.x + pi.z * w2.x + pi.w * w3.x;
            v.y = pi.x * w0.y + pi.y * w1.y + pi.z * w2.y + pi.w * w3.y;
            v.z = pi.x * w0.z + pi.y * w1.z + pi.z * w2.z + pi.w * w3.z;
            v.w = pi.x * w0.w + pi.y * w1.w + pi.z * w2.w + pi.w * w3.w;
            obase[(i * 4 + 0) * RLEN] = v.x;    // lanes: consecutive r -> coalesced
            obase[(i * 4 + 1) * RLEN] = v.y;
            obase[(i * 4 + 2) * RLEN] = v.z;
            obase[(i * 4 + 3) * RLEN] = v.w;
        }
    }
}

extern "C" void kernel_launch(void* const* d_in, const int* in_sizes, int n_in,
                              void* d_out, int out_size, void* d_ws, size_t ws_size,
                              hipStream_t stream) {
    const float* act   = (const float*)d_in[0];
    const float* poses = (const float*)d_in[1];
    const float* W     = (const float*)d_in[2];
    float* out = (float*)d_out;

    v8_kernel<<<1024, 256, 0, stream>>>(act, poses, W, out);
}